// Round 1
// baseline (978.242 us; speedup 1.0000x reference)
//
#include <hip/hip_runtime.h>

// ---------------------------------------------------------------------------
// SRU LM: emb-gather -> SRU(512->1024,k4) -> 4x SRU(1024,k3) -> SRU(1024->512,k4)
//         -> logits = h @ emb^T + bias
// L=128 B=32 E=512 D=1024 V=32000 MID=4
// All GEMMs: bf16 MFMA 16x16x32, C=A(M,K) * B^T(N,K), fp32 accum.
// U scratch lives in d_out (written last by the logits GEMM).
// ---------------------------------------------------------------------------

typedef __attribute__((ext_vector_type(8))) __bf16 bf16x8;
typedef __attribute__((ext_vector_type(4))) float f32x4;
typedef __attribute__((ext_vector_type(4))) float float4v;
typedef __attribute__((ext_vector_type(4))) unsigned short u16x4;

__device__ __forceinline__ unsigned short f2bf(float f) {
  unsigned int u = __builtin_bit_cast(unsigned int, f);
  u += 0x7fffu + ((u >> 16) & 1u);          // RNE
  return (unsigned short)(u >> 16);
}
__device__ __forceinline__ float bf2f(unsigned short v) {
  unsigned int u = ((unsigned int)v) << 16;
  return __builtin_bit_cast(float, u);
}

#define GLDS16(SRC, DST)                                                      \
  __builtin_amdgcn_global_load_lds(                                           \
      (__attribute__((address_space(1))) void*)(SRC),                         \
      (__attribute__((address_space(3))) void*)(DST), 16, 0, 0)

// ---------------------------------------------------------------------------
// GEMM: C[m][n] = sum_k A[m][k]*B[n][k] (+bias[n]).  A:(M,K) bf16, B:(N,K) bf16,
// C:(M,N) fp32.  M%128==0, N%128==0, K%64==0.
// 128x128 tile, BK=64, 256 thr (4 waves, 2x2), per-wave 64x64 = 4x4 frags.
// LDS slot-swizzle: LDS[row][slot] holds global 16B-slot (slot ^ (row&7)).
// Staged with global_load_lds (linear dest, pre-swizzled global source).
// ---------------------------------------------------------------------------
__global__ void gemm_bt(const unsigned short* __restrict__ A,
                        const unsigned short* __restrict__ B,
                        float* __restrict__ C,
                        const float* __restrict__ bias,
                        int M, int N, int K) {
  __shared__ unsigned short As[128 * 64];
  __shared__ unsigned short Bs[128 * 64];

  const int tid  = threadIdx.x;
  const int lane = tid & 63;
  const int wave = tid >> 6;
  const int wm = wave >> 1, wn = wave & 1;
  const int m0 = blockIdx.y * 128, n0 = blockIdx.x * 128;

  // staging: per call j, wave stages 8 rows; lane covers row (lane>>3),
  // LDS 16B-slot (lane&7); global slot pre-swizzled so LDS[r][s] = g-slot s^(r&7)
  const int srow  = lane >> 3;
  const int sslot = (lane & 7) ^ srow;

  // fragment reads: row = base + (lane&15); global slot G = (lane>>4) (+4 for kk=1)
  // LDS slot = G ^ (row&7) = G ^ (lane&7)
  const int fr = lane & 15;
  const int s0 = (lane >> 4) ^ (lane & 7);

  f32x4 acc[4][4] = {};

  const int ksteps = K >> 6;
  for (int ks = 0; ks < ksteps; ++ks) {
    const int k0 = ks << 6;
#pragma unroll
    for (int j = 0; j < 4; ++j) {
      const int rbase = (j * 4 + wave) * 8;          // wave-uniform
      const int r = rbase + srow;
      const unsigned short* sa = A + (size_t)(m0 + r) * K + k0 + sslot * 8;
      const unsigned short* sb = B + (size_t)(n0 + r) * K + k0 + sslot * 8;
      GLDS16(sa, &As[rbase * 64]);
      GLDS16(sb, &Bs[rbase * 64]);
    }
    __syncthreads();
#pragma unroll
    for (int kk = 0; kk < 2; ++kk) {
      const int slot = s0 ^ (kk << 2);
      bf16x8 a[4], b[4];
#pragma unroll
      for (int m = 0; m < 4; ++m)
        a[m] = *(const bf16x8*)&As[(wm * 64 + m * 16 + fr) * 64 + slot * 8];
#pragma unroll
      for (int n = 0; n < 4; ++n)
        b[n] = *(const bf16x8*)&Bs[(wn * 64 + n * 16 + fr) * 64 + slot * 8];
#pragma unroll
      for (int m = 0; m < 4; ++m)
#pragma unroll
        for (int n = 0; n < 4; ++n)
          acc[m][n] = __builtin_amdgcn_mfma_f32_16x16x32_bf16(a[m], b[n],
                                                              acc[m][n], 0, 0, 0);
    }
    __syncthreads();
  }

  const int lg = lane >> 4;
#pragma unroll
  for (int n = 0; n < 4; ++n) {
    const int col = n0 + wn * 64 + n * 16 + fr;
    const float bv = bias ? bias[col] : 0.0f;
#pragma unroll
    for (int m = 0; m < 4; ++m) {
#pragma unroll
      for (int r = 0; r < 4; ++r) {
        const int row = m0 + wm * 64 + m * 16 + lg * 4 + r;
        C[(size_t)row * N + col] = acc[m][n][r] + bv;
      }
    }
  }
}

// ---------------------------------------------------------------------------
// SRU scan: one thread per (b,d) chain, sequential over L=128.
// U:(L,B,k*n_out) fp32. hw = U[...,3n:] if k==4 else bf16 hin.
// writes bf16 h for the next GEMM.  hin==hout allowed when k==4 (unused read).
// ---------------------------------------------------------------------------
__global__ void scan_k(const float* __restrict__ U, const float* __restrict__ bias,
                       const float* __restrict__ c0, const unsigned short* hin,
                       unsigned short* hout, int n_out, int k) {
  const int idx = blockIdx.x * 256 + threadIdx.x;    // 0 .. 32*n_out
  const int b = idx / n_out;
  const int d = idx - b * n_out;
  const float biasf = bias[d];
  const float biasr = bias[n_out + d];
  float c = c0[idx];
  const int rowlen = k * n_out;
  const float* Up = U + (size_t)b * rowlen + d;
  const size_t lstride = (size_t)32 * rowlen;
  const unsigned short* hp = hin + (size_t)b * n_out + d;
  unsigned short* op = hout + (size_t)b * n_out + d;
  const size_t hstride = (size_t)32 * n_out;
  const bool k4 = (k == 4);
  for (int l = 0; l < 128; ++l) {
    const float xt = Up[0];
    const float fraw = Up[n_out];
    const float rraw = Up[2 * n_out];
    const float hw = k4 ? Up[3 * n_out] : bf2f(*hp);
    const float f = 1.0f / (1.0f + __expf(-(fraw + biasf)));
    const float r = 1.0f / (1.0f + __expf(-(rraw + biasr)));
    c = f * c + (1.0f - f) * xt;
    const float e2 = __expf(2.0f * c);
    const float g = 1.0f - 2.0f / (e2 + 1.0f);      // tanh(c)
    const float h = r * g + (1.0f - r) * hw;
    *op = f2bf(h);
    Up += lstride;
    hp += hstride;
    op += hstride;
  }
}

// fp32 (K,N) -> bf16 (N,K) transpose-convert.  K%32==0, N%32==0.
__global__ void transpose_k(const float* __restrict__ W,
                            unsigned short* __restrict__ Wt, int K, int N) {
  __shared__ float tile[32][33];
  const int n0 = blockIdx.x * 32, k0 = blockIdx.y * 32;
  const int tx = threadIdx.x, ty = threadIdx.y;   // (32,8)
#pragma unroll
  for (int i = 0; i < 32; i += 8)
    tile[ty + i][tx] = W[(size_t)(k0 + ty + i) * N + n0 + tx];
  __syncthreads();
#pragma unroll
  for (int i = 0; i < 32; i += 8)
    Wt[(size_t)(n0 + ty + i) * K + k0 + tx] = f2bf(tile[tx][ty + i]);
}

// fp32 -> bf16 elementwise, 4/thread
__global__ void cvt4(const float* __restrict__ in, unsigned short* __restrict__ out) {
  const int i = blockIdx.x * 256 + threadIdx.x;
  const float4v v = ((const float4v*)in)[i];
  u16x4 o;
  o.x = f2bf(v.x); o.y = f2bf(v.y); o.z = f2bf(v.z); o.w = f2bf(v.w);
  ((u16x4*)out)[i] = o;
}

// embedding gather -> bf16 (4096,512)
__global__ void embed_k(const int* __restrict__ x, const float* __restrict__ emb,
                        unsigned short* __restrict__ out) {
  const int i = blockIdx.x * 256 + threadIdx.x;   // 0..2097151
  const int row = i >> 9, e = i & 511;
  const int tok = x[row];
  out[i] = f2bf(emb[((size_t)tok << 9) + e]);
}

extern "C" void kernel_launch(void* const* d_in, const int* in_sizes, int n_in,
                              void* d_out, int out_size, void* d_ws, size_t ws_size,
                              hipStream_t stream) {
  (void)in_sizes; (void)n_in; (void)out_size; (void)ws_size;
  const int*   x     = (const int*)d_in[0];
  const float* c1    = (const float*)d_in[1];
  const float* c2    = (const float*)d_in[2];
  const float* c3    = (const float*)d_in[3];
  const float* emb   = (const float*)d_in[4];
  const float* obias = (const float*)d_in[5];
  const float* W1    = (const float*)d_in[6];
  const float* b1    = (const float*)d_in[7];
  const float* W2    = (const float*)d_in[8];
  const float* b2    = (const float*)d_in[9];
  const float* W3    = (const float*)d_in[10];
  const float* b3    = (const float*)d_in[11];

  char* ws = (char*)d_ws;
  unsigned short* hbfA  = (unsigned short*)ws;                  //  8,388,608 B
  unsigned short* hbfB  = (unsigned short*)(ws + 8388608);      //  8,388,608 B
  unsigned short* embbf = (unsigned short*)(ws + 16777216);     // 32,768,000 B
  unsigned short* Wt    = (unsigned short*)(ws + 49545216);     //  6,291,456 B
  float* U = (float*)d_out;   // up to 4096*4096 fp32 = 67 MB scratch, safe: d_out
                              // is only written (fully) by the final logits GEMM.

  // emb -> bf16 (B-operand of logits GEMM)
  cvt4<<<16000, 256, 0, stream>>>(emb, embbf);                  // 16,384,000 elems
  // token gather -> bf16 h0 (4096 x 512)
  embed_k<<<8192, 256, 0, stream>>>(x, emb, hbfA);

  // ---- layer 1: (512 -> 1024, k=4) ----
  transpose_k<<<dim3(128, 16), dim3(32, 8), 0, stream>>>(W1, Wt, 512, 4096);
  gemm_bt<<<dim3(32, 32), 256, 0, stream>>>(hbfA, Wt, U, nullptr, 4096, 4096, 512);
  scan_k<<<128, 256, 0, stream>>>(U, b1, c1, hbfB /*unused*/, hbfB, 1024, 4);

  // ---- mid layers: 4x (1024 -> 1024, k=3, hw = input) ----
  const unsigned short* hin = hbfB;
  unsigned short* hout = hbfA;
  for (int i = 0; i < 4; ++i) {
    transpose_k<<<dim3(96, 32), dim3(32, 8), 0, stream>>>(W2 + (size_t)i * 1024 * 3072,
                                                          Wt, 1024, 3072);
    gemm_bt<<<dim3(24, 32), 256, 0, stream>>>(hin, Wt, U, nullptr, 4096, 3072, 1024);
    scan_k<<<128, 256, 0, stream>>>(U, b2 + i * 2048, c2 + (size_t)i * 32768,
                                    hin, hout, 1024, 3);
    const unsigned short* t = hin; hin = hout; hout = (unsigned short*)t;
  }

  // ---- final SRU: (1024 -> 512, k=4) ----
  transpose_k<<<dim3(64, 32), dim3(32, 8), 0, stream>>>(W3, Wt, 1024, 2048);
  gemm_bt<<<dim3(16, 32), 256, 0, stream>>>(hin, Wt, U, nullptr, 4096, 2048, 1024);
  scan_k<<<64, 256, 0, stream>>>(U, b3, c3, hout /*unused*/, hout, 512, 4);

  // ---- logits: (4096 x 32000) = h5 @ emb^T + out_bias ----
  gemm_bt<<<dim3(250, 32), 256, 0, stream>>>(hout, embbf, (float*)d_out, obias,
                                             4096, 32000, 512);
}